// Round 2
// baseline (146.903 us; speedup 1.0000x reference)
//
#include <hip/hip_runtime.h>
#include <math.h>

#define VOCAB 50000
#define EMBED 128
#define SEQ   200
#define HID   30
#define BATCH 4096

__device__ __forceinline__ float tanh_fast(float x) {
    // tanh(x) = 1 - 2/(e^{2x}+1); safe for |x| large (inf -> 1, 0 -> -1)
    float e = __expf(2.0f * x);
    return 1.0f - 2.0f / (e + 1.0f);
}

// Kernel 1: embP[v][j] = sum_e emb[v][e] * Wx[e][j] + b_rnn[j]
// grid: ceil(VOCAB/8) x 256 threads (8 vocab rows per block, 32 lanes per row)
__global__ __launch_bounds__(256) void embproj_kernel(
    const float* __restrict__ emb, const float* __restrict__ Wx,
    const float* __restrict__ brnn, float* __restrict__ embP)
{
    __shared__ float WxL[EMBED * HID];
    __shared__ float bL[32];
    int tid = threadIdx.x;
    for (int i = tid; i < EMBED * HID; i += 256) WxL[i] = Wx[i];
    if (tid < HID) bL[tid] = brnn[tid];
    __syncthreads();

    int v = blockIdx.x * 8 + (tid >> 5);
    int j = tid & 31;
    if (v < VOCAB && j < HID) {
        const float4* e4 = (const float4*)(emb + (size_t)v * EMBED);
        float a0 = bL[j], a1 = 0.f, a2 = 0.f, a3 = 0.f;
        #pragma unroll
        for (int q = 0; q < EMBED / 4; ++q) {
            float4 e = e4[q];
            a0 += e.x * WxL[(4*q+0)*HID + j];
            a1 += e.y * WxL[(4*q+1)*HID + j];
            a2 += e.z * WxL[(4*q+2)*HID + j];
            a3 += e.w * WxL[(4*q+3)*HID + j];
        }
        embP[(size_t)v * HID + j] = (a0 + a1) + (a2 + a3);
    }
}

// Kernel 2: fused RNN recurrence over T + dense head.
// Block = 256 threads = 4 waves; each wave owns 2 batch rows (32 lanes/row).
// No cross-wave LDS sharing -> no __syncthreads in the time loop.
__global__ __launch_bounds__(256) void rnn_head_kernel(
    const int* __restrict__ tokens, const float* __restrict__ embP,
    const float* __restrict__ Wh,
    const float* __restrict__ W1, const float* __restrict__ b1,
    const float* __restrict__ W2, const float* __restrict__ b2,
    const float* __restrict__ W3, const float* __restrict__ b3,
    const float* __restrict__ Wo, const float* __restrict__ bo,
    float* __restrict__ out)
{
    __shared__ int   tokL[8][SEQ];
    __shared__ float hL[8][32];
    __shared__ float d1L[8][128];
    __shared__ float d2L[8][64];

    int tid = threadIdx.x;
    int r = tid >> 5;          // row within block (0..7); 2 rows per wave
    int j = tid & 31;          // lane within row
    int b = blockIdx.x * 8 + r;

    // stage this row's token sequence (coalesced within the 32-lane group)
    for (int i = j; i < SEQ; i += 32) tokL[r][i] = tokens[(size_t)b * SEQ + i];
    hL[r][j] = 0.0f;           // h0 = 0 (incl. pad cols 30,31)

    // each lane holds its Wh column: whc[k] = Wh[k][j]
    float whc[HID];
    #pragma unroll
    for (int k = 0; k < HID; ++k) whc[k] = (j < HID) ? Wh[k * HID + j] : 0.0f;

    // prefetch xp for t=0
    int tok0 = tokL[r][0];
    float xp = (j < HID) ? embP[(size_t)tok0 * HID + j] : 0.0f;

    for (int t = 0; t < SEQ; ++t) {
        // issue next step's gather early: latency hides under the FMA chain
        int tn = tokL[r][(t < SEQ - 1) ? t + 1 : SEQ - 1];
        float xpn = (j < HID) ? embP[(size_t)tn * HID + j] : 0.0f;

        // broadcast-read h_old (8x ds_read_b128, same addr across the row group)
        float hv[32];
        #pragma unroll
        for (int q = 0; q < 8; ++q) {
            float4 h4 = ((const float4*)hL[r])[q];
            hv[4*q+0] = h4.x; hv[4*q+1] = h4.y; hv[4*q+2] = h4.z; hv[4*q+3] = h4.w;
        }
        float a0 = xp, a1 = 0.0f;
        #pragma unroll
        for (int k = 0; k < HID; k += 2) {
            a0 += hv[k]     * whc[k];
            a1 += hv[k + 1] * whc[k + 1];
        }
        float hn = tanh_fast(a0 + a1);
        // in-wave DS ordering: all lanes' reads above precede this write
        if (j < HID) hL[r][j] = hn;
        xp = xpn;
    }

    // ---- dense head (one-time) ----
    // d1 = relu(h @ W1 + b1), 128 cols; lane j does cols j+32q
    #pragma unroll
    for (int q = 0; q < 4; ++q) {
        int c = j + 32 * q;
        float acc = b1[c];
        #pragma unroll
        for (int k = 0; k < HID; ++k) acc += hL[r][k] * W1[k * 128 + c];
        d1L[r][c] = fmaxf(acc, 0.0f);
    }
    // d2 = relu(d1 @ W2 + b2), 64 cols; lane j does cols j, j+32
    #pragma unroll
    for (int q = 0; q < 2; ++q) {
        int c = j + 32 * q;
        float acc = b2[c];
        #pragma unroll 8
        for (int k = 0; k < 128; ++k) acc += d1L[r][k] * W2[k * 64 + c];
        d2L[r][c] = fmaxf(acc, 0.0f);
    }
    // d3 = relu(d2 @ W3 + b3), 32 cols; lane j does col j. Then out = sigmoid(d3 @ Wo + bo)
    float acc3 = b3[j];
    #pragma unroll 8
    for (int k = 0; k < 64; ++k) acc3 += d2L[r][k] * W3[k * 32 + j];
    acc3 = fmaxf(acc3, 0.0f);
    float prod = acc3 * Wo[j];
    #pragma unroll
    for (int m = 16; m > 0; m >>= 1) prod += __shfl_xor(prod, m, 32);
    if (j == 0) out[b] = 1.0f / (1.0f + __expf(-(prod + bo[0])));
}

extern "C" void kernel_launch(void* const* d_in, const int* in_sizes, int n_in,
                              void* d_out, int out_size, void* d_ws, size_t ws_size,
                              hipStream_t stream) {
    (void)in_sizes; (void)n_in; (void)out_size; (void)ws_size;
    const int*   tokens = (const int*)  d_in[0];
    const float* emb    = (const float*)d_in[1];
    const float* Wx     = (const float*)d_in[2];
    const float* Wh     = (const float*)d_in[3];
    const float* brnn   = (const float*)d_in[4];
    const float* W1     = (const float*)d_in[5];
    const float* b1     = (const float*)d_in[6];
    const float* W2     = (const float*)d_in[7];
    const float* b2     = (const float*)d_in[8];
    const float* W3     = (const float*)d_in[9];
    const float* b3     = (const float*)d_in[10];
    const float* Wo     = (const float*)d_in[11];
    const float* bo     = (const float*)d_in[12];
    float* out  = (float*)d_out;
    float* embP = (float*)d_ws;   // 50000*30*4 = 6 MB

    embproj_kernel<<<(VOCAB + 7) / 8, 256, 0, stream>>>(emb, Wx, brnn, embP);
    rnn_head_kernel<<<BATCH / 8, 256, 0, stream>>>(
        tokens, embP, Wh, W1, b1, W2, b2, W3, b3, Wo, bo, out);
}

// Round 4
// 121.271 us; speedup vs baseline: 1.2114x; 1.2114x over previous
//
#include <hip/hip_runtime.h>
#include <math.h>

#define VOCAB 50000
#define EMBED 128
#define SEQ   200
#define HID   30
#define BATCH 4096

// NUMERICS FROZEN (matches round-2 pass, absmax 7.8e-3 @ threshold 1.05e-2):
// the 200-step tanh recurrence amplifies per-step rounding ~1e5x, so every
// FP op sequence below must stay bit-identical. Only scheduling may change.
__device__ __forceinline__ float tanh_fast(float x) {
    // tanh(x) = 1 - 2/(e^{2x}+1); IEEE divide (NOT __fdividef - accuracy).
    float e = __expf(2.0f * x);
    return 1.0f - 2.0f / (e + 1.0f);
}

// Kernel 1: embP[v][j] = sum_e emb[v][e] * Wx[e][j] + b_rnn[j]
// 8 groups of 32 lanes; each group does 4 vocab rows (LDS reads amortized x4).
// Per-(v,j) accumulation sequence identical to the round-2 kernel:
//   a_d += e[4q+d] * Wx[4q+d][j], result (a0+a1)+(a2+a3).
__global__ __launch_bounds__(256) void embproj_kernel(
    const float* __restrict__ emb, const float* __restrict__ Wx,
    const float* __restrict__ brnn, float* __restrict__ embP)
{
    __shared__ float WxL[EMBED * HID];
    __shared__ float bL[32];
    int tid = threadIdx.x;
    for (int i = tid; i < EMBED * HID; i += 256) WxL[i] = Wx[i];
    if (tid < HID) bL[tid] = brnn[tid];
    __syncthreads();

    int g  = tid >> 5;
    int j  = tid & 31;
    int jj = (j < HID) ? j : 0;        // clamp LDS column for pad lanes
    int v0 = blockIdx.x * 32 + g * 4;

    int vr0 = min(v0 + 0, VOCAB - 1);
    int vr1 = min(v0 + 1, VOCAB - 1);
    int vr2 = min(v0 + 2, VOCAB - 1);
    int vr3 = min(v0 + 3, VOCAB - 1);
    const float4* e0 = (const float4*)(emb + (size_t)vr0 * EMBED);
    const float4* e1 = (const float4*)(emb + (size_t)vr1 * EMBED);
    const float4* e2 = (const float4*)(emb + (size_t)vr2 * EMBED);
    const float4* e3 = (const float4*)(emb + (size_t)vr3 * EMBED);

    float bj = (j < HID) ? bL[jj] : 0.0f;
    // acc[row][d]; d-th accumulator gets bias only for d==0 (round-2 order)
    float acc[4][4];
    #pragma unroll
    for (int rr = 0; rr < 4; ++rr) {
        acc[rr][0] = bj; acc[rr][1] = 0.f; acc[rr][2] = 0.f; acc[rr][3] = 0.f;
    }

    #pragma unroll 4
    for (int q = 0; q < EMBED / 4; ++q) {
        float4 r0 = e0[q], r1 = e1[q], r2 = e2[q], r3 = e3[q];
        #pragma unroll
        for (int d = 0; d < 4; ++d) {
            float w = WxL[(4 * q + d) * HID + jj];
            acc[0][d] += (&r0.x)[d] * w;
            acc[1][d] += (&r1.x)[d] * w;
            acc[2][d] += (&r2.x)[d] * w;
            acc[3][d] += (&r3.x)[d] * w;
        }
    }
    if (j < HID) {
        #pragma unroll
        for (int rr = 0; rr < 4; ++rr) {
            if (v0 + rr < VOCAB)
                embP[(size_t)(v0 + rr) * HID + j] =
                    (acc[rr][0] + acc[rr][1]) + (acc[rr][2] + acc[rr][3]);
        }
    }
}

// Kernel 2: fused RNN recurrence + dense head.
// 1 batch row per WAVE (lanes 32-63 compute redundantly; writes gated) ->
// 4096 waves = 4/SIMD. embP gathers prefetched 8 steps ahead (ring of 8).
// Per-step FP sequence identical to round 2: two 15-FMA chains (even/odd k),
// a0 seeded with xp, tanh via __expf + IEEE divide.
// All LDS traffic is wave-private -> no barriers in the time loop.
__global__ __launch_bounds__(256, 4) void rnn_head_kernel(
    const int* __restrict__ tokens, const float* __restrict__ embP,
    const float* __restrict__ Wh,
    const float* __restrict__ W1, const float* __restrict__ b1,
    const float* __restrict__ W2, const float* __restrict__ b2,
    const float* __restrict__ W3, const float* __restrict__ b3,
    const float* __restrict__ Wo, const float* __restrict__ bo,
    float* __restrict__ out)
{
    __shared__ int   tokL[4][SEQ];
    __shared__ float hL[4][32];
    __shared__ float d1L[4][128];
    __shared__ float d2L[4][64];

    int tid = threadIdx.x;
    int r   = tid >> 6;          // wave (= batch row) within block, 0..3
    int l   = tid & 63;
    int j   = l & 31;            // output column (lanes 32-63 mirror 0-31)
    int b   = blockIdx.x * 4 + r;

    for (int i = l; i < SEQ; i += 64) tokL[r][i] = tokens[(size_t)b * SEQ + i];
    if (l < 32) hL[r][l] = 0.0f;     // h0 = 0, incl. pad cols 30,31

    float whc[HID];
    #pragma unroll
    for (int k = 0; k < HID; ++k) whc[k] = (j < HID) ? Wh[k * HID + j] : 0.0f;

    bool ld = (j < HID);
    // prefetch ring: xq[s] holds xp for step t+s (8 loads in flight)
    float xq[8];
    #pragma unroll
    for (int s = 0; s < 8; ++s) {
        int tk = tokL[r][s];
        xq[s] = ld ? embP[(size_t)tk * HID + j] : 0.0f;
    }

    for (int t = 0; t < SEQ; t += 8) {
        #pragma unroll
        for (int s = 0; s < 8; ++s) {
            // token for the step 8 ahead (ds_read off the critical path)
            int tf = t + 8 + s; tf = (tf < SEQ) ? tf : SEQ - 1;
            int tk = tokL[r][tf];

            // wave-private broadcast read of h (8x ds_read_b128)
            float hv[32];
            const float4* h4 = (const float4*)hL[r];
            #pragma unroll
            for (int q = 0; q < 8; ++q) {
                float4 h = h4[q];
                hv[4*q+0] = h.x; hv[4*q+1] = h.y; hv[4*q+2] = h.z; hv[4*q+3] = h.w;
            }
            float a0 = xq[s], a1 = 0.0f;
            #pragma unroll
            for (int k = 0; k < HID; k += 2) {
                a0 += hv[k]     * whc[k];
                a1 += hv[k + 1] * whc[k + 1];
            }
            float hn = tanh_fast(a0 + a1);
            if (l < HID) hL[r][l] = hn;   // lanes 0..29 write; in-wave DS order
            // refill ring slot for step t+8+s
            xq[s] = ld ? embP[(size_t)tk * HID + j] : 0.0f;
        }
    }

    // ---- dense head: lanes 0-31 only, round-2 sequence exactly ----
    if (l < 32) {
        #pragma unroll
        for (int q = 0; q < 4; ++q) {
            int c = l + 32 * q;
            float acc = b1[c];
            #pragma unroll
            for (int k = 0; k < HID; ++k) acc += hL[r][k] * W1[k * 128 + c];
            d1L[r][c] = fmaxf(acc, 0.0f);
        }
        #pragma unroll
        for (int q = 0; q < 2; ++q) {
            int c = l + 32 * q;
            float acc = b2[c];
            #pragma unroll 8
            for (int k = 0; k < 128; ++k) acc += d1L[r][k] * W2[k * 64 + c];
            d2L[r][c] = fmaxf(acc, 0.0f);
        }
        float acc3 = b3[l];
        #pragma unroll 8
        for (int k = 0; k < 64; ++k) acc3 += d2L[r][k] * W3[k * 32 + l];
        acc3 = fmaxf(acc3, 0.0f);
        float prod = acc3 * Wo[l];
        #pragma unroll
        for (int m = 16; m > 0; m >>= 1) prod += __shfl_xor(prod, m, 32);
        if (l == 0) out[b] = 1.0f / (1.0f + __expf(-(prod + bo[0])));
    }
}

extern "C" void kernel_launch(void* const* d_in, const int* in_sizes, int n_in,
                              void* d_out, int out_size, void* d_ws, size_t ws_size,
                              hipStream_t stream) {
    (void)in_sizes; (void)n_in; (void)out_size; (void)ws_size;
    const int*   tokens = (const int*)  d_in[0];
    const float* emb    = (const float*)d_in[1];
    const float* Wx     = (const float*)d_in[2];
    const float* Wh     = (const float*)d_in[3];
    const float* brnn   = (const float*)d_in[4];
    const float* W1     = (const float*)d_in[5];
    const float* b1     = (const float*)d_in[6];
    const float* W2     = (const float*)d_in[7];
    const float* b2     = (const float*)d_in[8];
    const float* W3     = (const float*)d_in[9];
    const float* b3     = (const float*)d_in[10];
    const float* Wo     = (const float*)d_in[11];
    const float* bo     = (const float*)d_in[12];
    float* out  = (float*)d_out;
    float* embP = (float*)d_ws;   // 50000*30*4 = 6 MB

    embproj_kernel<<<(VOCAB + 31) / 32, 256, 0, stream>>>(emb, Wx, brnn, embP);
    rnn_head_kernel<<<BATCH / 4, 256, 0, stream>>>(
        tokens, embP, Wh, W1, b1, W2, b2, W3, b3, Wo, bo, out);
}